// Round 5
// baseline (392.257 us; speedup 1.0000x reference)
//
#include <hip/hip_runtime.h>

#define NGRID 8192
#define NLAYER 24
#define NPERIODS 50
#define NOBS 4096
#define NC 200
#define PP 64            // r_pad row padded to 64 (zero for p>=50)
#define NSPLIT 16        // g-splits across blockIdx.y in K2
#define GC (NGRID / NSPLIT)   // 512 g per block
#define KG 32            // g subtile staged in LDS per block
#define NKT (GC / KG)    // 16 k-tiles
#define ASTR 36          // LDS stride: 0 bank conflicts measured (R1/R4)
#define WPB 8            // waves per block in K2
#define NPW 7            // periods per wave (8*7=56 >= 50; pad reads are 0)
#define ESTR 201         // k3 LDS row stride (odd -> <=2-way conflicts)
#define NBINS 1024
#define OTILE 64
#define VREF 3.0f

// ---------------- K1: r_pad[g][p] = 1/(0.92 * sum_l w[p][l]*Vs[g][l]); block 0 zeroes bins ----------------
__global__ __launch_bounds__(256) void k1_rpad(const float* __restrict__ Vs,
                                               const float* __restrict__ thick,
                                               const float* __restrict__ periods,
                                               float* __restrict__ r_pad,
                                               float* __restrict__ bins) {
    __shared__ float w_sh[NLAYER][NPERIODS];   // transposed: reads are conflict-free
    __shared__ float z_sh[NLAYER];
    int tid = threadIdx.x;
    if (blockIdx.x == 0) {
        for (int i = tid; i < NBINS; i += 256) bins[i] = 0.f;
    }
    if (tid < NLAYER) {
        float c = 0.f;
        for (int i = 0; i <= tid; ++i) c += thick[i];
        z_sh[tid] = c - 0.5f * thick[tid];
    }
    __syncthreads();
    if (tid < NPERIODS) {
        float ds = (VREF / 3.0f) * periods[tid];
        float tmp[NLAYER];
        float s = 0.f;
        #pragma unroll
        for (int l = 0; l < NLAYER; ++l) {
            float v = expf(-z_sh[l] / ds) * thick[l];
            tmp[l] = v; s += v;
        }
        float inv = 1.f / s;
        #pragma unroll
        for (int l = 0; l < NLAYER; ++l) w_sh[l][tid] = tmp[l] * inv;
    }
    __syncthreads();
    int idx = blockIdx.x * 256 + tid;          // idx = g*64 + p  (lanes share g -> broadcast Vs)
    int g = idx >> 6, p = idx & 63;
    float r = 0.f;
    if (p < NPERIODS) {
        const float4* vp = (const float4*)(Vs + (size_t)g * NLAYER);
        float s = 0.f;
        #pragma unroll
        for (int q = 0; q < NLAYER / 4; ++q) {
            float4 t = vp[q];
            s = fmaf(w_sh[4*q+0][p], t.x, s);
            s = fmaf(w_sh[4*q+1][p], t.y, s);
            s = fmaf(w_sh[4*q+2][p], t.z, s);
            s = fmaf(w_sh[4*q+3][p], t.w, s);
        }
        r = 1.0f / (0.92f * s);
    }
    r_pad[idx] = r;                            // fully coalesced, zero-padded p>=50
}

// ---------------- K2: partial_t[s][p][o] = sum_{g in split s} A[o][g]*r[g][p] ----------------
// lane <-> obs; 8 waves split 50 periods (7 each) and share one block A-tile.
// acc[7] => ~24 VGPR (spill-proof: R2/R3 lesson). 1024 blocks x 8 waves =
// 4 blocks/CU = 32 waves/CU = 8 waves/SIMD to hide the uniform s_load latency
// of r (R4 lesson: 4 waves/SIMD left VALUBusy at 24%). Double-buffered A tile,
// one barrier per k-tile, next tile's global load issued before compute.
__global__ __launch_bounds__(512) void k2_gemm(const float* __restrict__ A,
                                               const float* __restrict__ r_pad,
                                               float* __restrict__ partial_t) {
    __shared__ float Aw[2][OTILE * ASTR];                  // 2 x 9216 B
    int tid  = threadIdx.x;
    int lane = tid & 63;
    int wv   = __builtin_amdgcn_readfirstlane(tid >> 6);   // uniform -> s_load of r
    int o_base = blockIdx.x * OTILE;
    int split  = blockIdx.y;
    int pbase  = wv * NPW;                                 // 0,7,...,49

    float acc[NPW];
    #pragma unroll
    for (int p = 0; p < NPW; ++p) acc[p] = 0.f;

    int g_blk = split * GC;
    // staging geometry: 512 threads x float4 cover 64 rows x 32 g exactly
    int srow = tid >> 3;
    int sc4  = (tid & 7) * 4;
    const float* Abase = A + (size_t)(o_base + srow) * NGRID + sc4 + g_blk;

    // preload tile 0
    {
        float4 t = *(const float4*)(Abase);
        *(float4*)(&Aw[0][srow * ASTR + sc4]) = t;
    }

    #pragma unroll 1
    for (int kt = 0; kt < NKT; ++kt) {
        int cur = kt & 1;
        __syncthreads();                                   // tile cur ready; buf cur^1 free
        int ktn = (kt + 1 < NKT) ? kt + 1 : NKT - 1;       // clamped prefetch (branchless)
        float4 tnext = *(const float4*)(Abase + ktn * KG);

        int g0 = g_blk + kt * KG;
        #pragma unroll 1
        for (int gg = 0; gg < KG; gg += 4) {
            float4 a4 = *(const float4*)(&Aw[cur][lane * ASTR + gg]);
            const float* rr = r_pad + (size_t)(g0 + gg) * PP + pbase;  // uniform -> s_load
            #pragma unroll
            for (int j = 0; j < 4; ++j) {
                float aj = (j == 0) ? a4.x : (j == 1) ? a4.y : (j == 2) ? a4.z : a4.w;
                #pragma unroll
                for (int p = 0; p < NPW; ++p)
                    acc[p] = fmaf(aj, rr[j * PP + p], acc[p]);   // p>=50 reads pad=0
            }
        }
        *(float4*)(&Aw[cur ^ 1][srow * ASTR + sc4]) = tnext;
    }

    // epilogue: each wave owns its p's -> direct coalesced stores
    float* outp = partial_t + (size_t)split * (NPERIODS * NOBS);
    #pragma unroll
    for (int p = 0; p < NPW; ++p) {
        int pp = pbase + p;
        if (pp < NPERIODS)
            outp[(size_t)pp * NOBS + o_base + lane] = acc[p];
    }
}

// ---------------- K2b: cpred_t[p][o] = 1 / sum_s partial_t[s][p][o]  (fully coalesced) ----------------
__global__ __launch_bounds__(256) void k2b_reduce(const float* __restrict__ partial_t,
                                                  float* __restrict__ cpred_t) {
    int idx = blockIdx.x * 256 + threadIdx.x;              // < 50*4096
    float s = 0.f;
    #pragma unroll
    for (int sp = 0; sp < NSPLIT; ++sp)
        s += partial_t[(size_t)sp * (NPERIODS * NOBS) + idx];
    cpred_t[idx] = 1.0f / s;
}

// ---------------- K3: block per obs. Stage energy (40KB) + c_axis into LDS;
// lane <-> period, 4 waves split the 200 c-columns; per-c work = 2 conflict-free
// ds_read_b32 + fmax + cmp. No divergent idle lanes, no deep shuffle chains. ----------------
__global__ __launch_bounds__(256) void k3_main(const float* __restrict__ energy,
                                               const float* __restrict__ c_axis,
                                               const float* __restrict__ cpred_t,
                                               float* __restrict__ bins) {
    __shared__ float esh[NPERIODS * ESTR];     // 40200 B
    __shared__ float csh[NC];                  // 800 B
    __shared__ float cpsh[64];
    __shared__ float cntp[4][64];
    __shared__ float maxp[4][64];
    int tid  = threadIdx.x;
    int lane = tid & 63;
    int wv   = tid >> 6;
    int o    = blockIdx.x;

    // stage: energy row-block (coalesced float4 reads, scalar LDS writes to padded rows)
    const float* eb = energy + (size_t)o * NPERIODS * NC;
    for (int i = tid; i < (NPERIODS * NC) / 4; i += 256) { // 2500 float4s
        int r_ = i / 50;                                   // row (0..49)
        int c_ = (i - r_ * 50) * 4;                        // col (multiple of 4)
        float4 v = *(const float4*)(eb + (size_t)i * 4);
        float* d = esh + r_ * ESTR + c_;
        d[0] = v.x; d[1] = v.y; d[2] = v.z; d[3] = v.w;
    }
    if (tid < NC) csh[tid] = c_axis[(size_t)o * NC + tid];
    if (tid < 64) cpsh[tid] = (tid < NPERIODS) ? cpred_t[(size_t)tid * NOBS + o] : 0.f;
    __syncthreads();

    // scan: lane = period, wave wv covers c in [wv*50, wv*50+50)
    int pr = lane < NPERIODS ? lane : 0;       // lanes 50-63 duplicate row 0 (broadcast, unused)
    float cp = cpsh[lane];
    float mx = -1e30f, cnt = 0.f;
    int cbase = wv * 50;
    #pragma unroll 2
    for (int c = 0; c < 50; ++c) {
        float ev  = esh[pr * ESTR + cbase + c];            // <=2-way banked (stride 201)
        float cav = csh[cbase + c];                        // broadcast
        mx = fmaxf(mx, ev);
        cnt += (cav < cp) ? 1.f : 0.f;
    }
    cntp[wv][lane] = cnt;
    maxp[wv][lane] = mx;
    __syncthreads();

    // combine on wave 0: lane = period
    float contrib = 0.f;
    if (wv == 0) {
        if (lane < NPERIODS) {
            float ct = cntp[0][lane] + cntp[1][lane] + cntp[2][lane] + cntp[3][lane];
            float m  = fmaxf(fmaxf(maxp[0][lane], maxp[1][lane]),
                             fmaxf(maxp[2][lane], maxp[3][lane]));
            int idx = (int)ct;
            idx = idx < 1 ? 1 : (idx > NC - 1 ? NC - 1 : idx);
            float c0 = csh[idx - 1], c1 = csh[idx];
            float e0 = esh[lane * ESTR + idx - 1], e1 = esh[lane * ESTR + idx];
            float w  = (cp - c0) / (c1 - c0 + 1e-12f);
            contrib = m - fmaf(w, e1 - e0, e0);
        }
        #pragma unroll
        for (int m2 = 32; m2; m2 >>= 1) contrib += __shfl_xor(contrib, m2, 64);
        if (lane == 0) atomicAdd(&bins[o & (NBINS - 1)], contrib);
    }
}

// ---------------- K4: final reduce of bins -> out ----------------
__global__ __launch_bounds__(256) void k4_final(const float* __restrict__ bins,
                                                float* __restrict__ out) {
    __shared__ float red[4];
    int tid = threadIdx.x;
    float s = 0.f;
    for (int i = tid; i < NBINS; i += 256) s += bins[i];
    #pragma unroll
    for (int m = 32; m; m >>= 1) s += __shfl_xor(s, m, 64);
    int lane = tid & 63, wv = tid >> 6;
    if (lane == 0) red[wv] = s;
    __syncthreads();
    if (tid == 0) out[0] = -(red[0] + red[1] + red[2] + red[3]);  // / SIGMA^2 == 1
}

extern "C" void kernel_launch(void* const* d_in, const int* in_sizes, int n_in,
                              void* d_out, int out_size, void* d_ws, size_t ws_size,
                              hipStream_t stream) {
    const float* Vs      = (const float*)d_in[0];
    const float* A       = (const float*)d_in[1];
    const float* energy  = (const float*)d_in[2];
    const float* c_axis  = (const float*)d_in[3];
    const float* thick   = (const float*)d_in[4];
    const float* periods = (const float*)d_in[5];
    float* out = (float*)d_out;

    float* ws        = (float*)d_ws;
    float* r_pad     = ws;                                          // 2 MB
    float* partial_t = r_pad + (size_t)NGRID * PP;                  // 13.1 MB
    float* cpred_t   = partial_t + (size_t)NSPLIT * NPERIODS * NOBS;// 800 KB
    float* bins      = cpred_t + (size_t)NPERIODS * NOBS;           // 4 KB

    hipLaunchKernelGGL(k1_rpad, dim3((NGRID * 64) / 256), dim3(256), 0, stream,
                       Vs, thick, periods, r_pad, bins);
    hipLaunchKernelGGL(k2_gemm, dim3(NOBS / OTILE, NSPLIT), dim3(512), 0, stream,
                       A, r_pad, partial_t);
    hipLaunchKernelGGL(k2b_reduce, dim3((NPERIODS * NOBS) / 256), dim3(256), 0, stream,
                       partial_t, cpred_t);
    hipLaunchKernelGGL(k3_main, dim3(NOBS), dim3(256), 0, stream,
                       energy, c_axis, cpred_t, bins);
    hipLaunchKernelGGL(k4_final, dim3(1), dim3(256), 0, stream, bins, out);
}